// Round 8
// baseline (64.170 us; speedup 1.0000x reference)
//
#include <hip/hip_runtime.h>
#include <hip/hip_fp16.h>

// Damped electrostatics with shifted-force cutoff.
// Packed atom table in d_ws, 32 B/atom (3.2 MB, L2-resident):
//   word0 (f32x4): q, dip.x, dip.y, dip.z
//   word1 (u32x4): fp16x2{t00,t11}, fp16x2{t22,s01}, fp16x2{s02,s12}, pad
//     t_ii = Q_ii - trQ/3 (traceless diag), s_ij = Q_ij + Q_ji.
// 4 edges per thread: coalesced f32x4/i32x4 streams + 12 independent gathers
// in flight -> memory-level parallelism against L2 gather latency.
// d recomputed from vec (d == |v| by construction).

#define CUTOFF      10.0f
#define KEHALF      7.199822675975274f

typedef float    f32x4 __attribute__((ext_vector_type(4)));
typedef int      i32x4 __attribute__((ext_vector_type(4)));
typedef unsigned u32x4 __attribute__((ext_vector_type(4)));

__device__ __forceinline__ unsigned pack_h2(float a, float b) {
    return __builtin_bit_cast(unsigned, __floats2half2_rn(a, b));
}
__device__ __forceinline__ float2 unpack_h2(unsigned u) {
    return __half22float2(__builtin_bit_cast(__half2, u));
}

__global__ __launch_bounds__(256) void pack_atoms_kernel(
    const float* __restrict__ q,
    const float* __restrict__ dip,
    const float* __restrict__ quad,
    f32x4* __restrict__ table,        // [N,2] 16B words
    int N)
{
    int i = blockIdx.x * blockDim.x + threadIdx.x;
    if (i >= N) return;
    const float* dp = dip + 3 * (size_t)i;
    const float* qp = quad + 9 * (size_t)i;

    f32x4 w0 = {q[i], dp[0], dp[1], dp[2]};

    float q00 = qp[0], q01 = qp[1], q02 = qp[2];
    float q10 = qp[3], q11 = qp[4], q12 = qp[5];
    float q20 = qp[6], q21 = qp[7], q22 = qp[8];
    float trQ3 = (q00 + q11 + q22) * (1.0f / 3.0f);

    u32x4 w1 = {pack_h2(q00 - trQ3, q11 - trQ3),
                pack_h2(q22 - trQ3, q01 + q10),
                pack_h2(q02 + q20, q12 + q21),
                0u};

    table[2 * (size_t)i + 0] = w0;
    table[2 * (size_t)i + 1] = __builtin_bit_cast(f32x4, w1);
}

__device__ __forceinline__ float edge_energy(
    float vx, float vy, float vz,
    f32x4 au, f32x4 av, u32x4 bv)
{
    float d2 = vx * vx + vy * vy + vz * vz;
    float d = sqrtf(d2);
    float inv_d = 1.0f / d;
    float inv_d2 = inv_d * inv_d;

    // poly5 switch, cutoff_sr = 4
    float x = d * 0.25f;
    float x2 = x * x;
    float x3 = x2 * x;
    float sw = 1.0f - x3 * (10.0f - 15.0f * x + 6.0f * x2);
    sw = (x < 1.0f) ? sw : 0.0f;
    float chi = sw * rsqrtf(d2 + 1.0f) + (1.0f - sw) * inv_d;

    // shifted-force corrections (cutoff = 10)
    float c1 = chi - (0.2f   - 0.01f   * d);
    float chi2 = chi * chi;
    float chi3 = chi2 * chi;
    float c2 = chi2 - (0.03f  - 0.002f  * d);
    float c3 = chi3 - (0.004f - 0.0003f * d);

    float qu = au.x, qv = av.x;
    float Ee = qu * qv * c1;

    float dot_uv = (vx * av.y + vy * av.z + vz * av.w) * inv_d;
    float dot_vu = (vx * au.y + vy * au.z + vz * au.w) * inv_d;
    float dd     = au.y * av.y + au.z * av.z + au.w * av.w;

    Ee += 2.0f * qu * dot_uv * c2;
    Ee += (dd - 3.0f * dot_uv * dot_vu) * c3;

    // traceless quadrupole contraction (uses sum(v_i^2) == d^2)
    float2 h0 = unpack_h2(bv.x);   // t00, t11
    float2 h1 = unpack_h2(bv.y);   // t22, s01
    float2 h2 = unpack_h2(bv.z);   // s02, s12
    float num = h0.x * vx * vx + h0.y * vy * vy + h1.x * vz * vz
              + h1.y * vx * vy + h2.x * vx * vz + h2.y * vy * vz;
    Ee += qu * (num * inv_d2) * c3;

    Ee *= KEHALF;
    return (d <= CUTOFF) ? Ee : 0.0f;
}

__global__ __launch_bounds__(256, 4) void damped_elec_4e(
    const f32x4* __restrict__ table,  // [N,2]
    const float* __restrict__ vec,    // [E,3]
    const int*   __restrict__ idx_u,  // [E]
    const int*   __restrict__ idx_v,  // [E]
    float*       __restrict__ out,    // [E]
    int E)
{
    int t = blockIdx.x * blockDim.x + threadIdx.x;
    size_t base = 4 * (size_t)t;

    if (base + 3 < (size_t)E) {
        // coalesced non-temporal streams
        i32x4 u4 = __builtin_nontemporal_load((const i32x4*)(idx_u + base));
        i32x4 v4 = __builtin_nontemporal_load((const i32x4*)(idx_v + base));
        const f32x4* vp = (const f32x4*)(vec + 3 * base);
        f32x4 w0 = __builtin_nontemporal_load(vp + 0);   // vx0 vy0 vz0 vx1
        f32x4 w1 = __builtin_nontemporal_load(vp + 1);   // vy1 vz1 vx2 vy2
        f32x4 w2 = __builtin_nontemporal_load(vp + 2);   // vz2 vx3 vy3 vz3

        int us[4] = {u4.x, u4.y, u4.z, u4.w};
        int vs[4] = {v4.x, v4.y, v4.z, v4.w};

        // issue all 12 gathers back-to-back (L2-resident table)
        f32x4 au[4], av[4], bv[4];
#pragma unroll
        for (int e = 0; e < 4; ++e) {
            au[e] = table[2 * (size_t)us[e]];
            av[e] = table[2 * (size_t)vs[e] + 0];
            bv[e] = table[2 * (size_t)vs[e] + 1];
        }

        float r0 = edge_energy(w0.x, w0.y, w0.z, au[0], av[0], __builtin_bit_cast(u32x4, bv[0]));
        float r1 = edge_energy(w0.w, w1.x, w1.y, au[1], av[1], __builtin_bit_cast(u32x4, bv[1]));
        float r2 = edge_energy(w1.z, w1.w, w2.x, au[2], av[2], __builtin_bit_cast(u32x4, bv[2]));
        float r3 = edge_energy(w2.y, w2.z, w2.w, au[3], av[3], __builtin_bit_cast(u32x4, bv[3]));

        f32x4 res = {r0, r1, r2, r3};
        __builtin_nontemporal_store(res, (f32x4*)(out + base));
    } else {
        for (size_t i = base; i < (size_t)E; ++i) {
            int u = idx_u[i];
            int v = idx_v[i];
            float vx = vec[3 * i + 0];
            float vy = vec[3 * i + 1];
            float vz = vec[3 * i + 2];
            out[i] = edge_energy(vx, vy, vz,
                                 table[2 * (size_t)u],
                                 table[2 * (size_t)v],
                                 __builtin_bit_cast(u32x4, table[2 * (size_t)v + 1]));
        }
    }
}

// Fallback if ws_size is too small for the packed table.
__global__ __launch_bounds__(256) void damped_elec_unpacked(
    const float* __restrict__ q,
    const float* __restrict__ dip,
    const float* __restrict__ quad,
    const float* __restrict__ vec,
    const int*   __restrict__ idx_u,
    const int*   __restrict__ idx_v,
    float*       __restrict__ out,
    int E)
{
    int i = blockIdx.x * blockDim.x + threadIdx.x;
    if (i >= E) return;
    float vx = vec[3 * (size_t)i + 0];
    float vy = vec[3 * (size_t)i + 1];
    float vz = vec[3 * (size_t)i + 2];
    int u = idx_u[i];
    int v = idx_v[i];
    const float* pu = dip + 3 * (size_t)u;
    const float* pv = dip + 3 * (size_t)v;
    const float* pq = quad + 9 * (size_t)v;

    f32x4 au = {q[u], pu[0], pu[1], pu[2]};
    f32x4 av = {q[v], pv[0], pv[1], pv[2]};
    float trQ3 = (pq[0] + pq[4] + pq[8]) * (1.0f / 3.0f);
    u32x4 bv = {pack_h2(pq[0] - trQ3, pq[4] - trQ3),
                pack_h2(pq[8] - trQ3, pq[1] + pq[3]),
                pack_h2(pq[2] + pq[6], pq[5] + pq[7]),
                0u};
    out[i] = edge_energy(vx, vy, vz, au, av, bv);
}

extern "C" void kernel_launch(void* const* d_in, const int* in_sizes, int n_in,
                              void* d_out, int out_size, void* d_ws, size_t ws_size,
                              hipStream_t stream) {
    const float* q    = (const float*)d_in[0];  // atomic_charges      [N]
    const float* dip  = (const float*)d_in[1];  // atomic_dipoles      [N,3]
    const float* quad = (const float*)d_in[2];  // atomic_quadrupoles  [N,3,3]
    const float* vec  = (const float*)d_in[3];  // vectors_uv          [E,3]
    const int*   iu   = (const int*)d_in[5];    // idx_u               [E]
    const int*   iv   = (const int*)d_in[6];    // idx_v               [E]
    float* out = (float*)d_out;

    int N = in_sizes[0];
    int E = in_sizes[4];
    int block = 256;

    size_t need = (size_t)N * 32;
    if (ws_size >= need) {
        f32x4* table = (f32x4*)d_ws;
        int pgrid = (N + block - 1) / block;
        pack_atoms_kernel<<<pgrid, block, 0, stream>>>(q, dip, quad, table, N);
        int nthreads = (E + 3) / 4;
        int egrid = (nthreads + block - 1) / block;
        damped_elec_4e<<<egrid, block, 0, stream>>>(table, vec, iu, iv, out, E);
    } else {
        int egrid = (E + block - 1) / block;
        damped_elec_unpacked<<<egrid, block, 0, stream>>>(q, dip, quad, vec, iu, iv, out, E);
    }
}

// Round 9
// 56.384 us; speedup vs baseline: 1.1381x; 1.1381x over previous
//
#include <hip/hip_runtime.h>
#include <hip/hip_fp16.h>

// Damped electrostatics with shifted-force cutoff.
// Packed atom table in d_ws, 32 B/atom (3.2 MB, L2-resident per XCD):
//   word0 (f32x4): q, dip.x, dip.y, dip.z
//   word1 (u32x4): fp16x2{t00,t11}, fp16x2{t22,s01}, fp16x2{s02,s12}, pad
//     t_ii = Q_ii - trQ/3 (traceless diag), s_ij = Q_ij + Q_ji.
// Edge kernel: 1 edge per grid-stride iteration, software-pipelined —
// next iteration's stream loads (idx/vec, non-temporal) are issued while
// the current iteration's gathers are being consumed, so the wave waits
// with vmcnt(N) instead of draining. d recomputed from vec (d == |v|).

#define CUTOFF      10.0f
#define KEHALF      7.199822675975274f

typedef float    f32x4 __attribute__((ext_vector_type(4)));
typedef unsigned u32x4 __attribute__((ext_vector_type(4)));

__device__ __forceinline__ unsigned pack_h2(float a, float b) {
    return __builtin_bit_cast(unsigned, __floats2half2_rn(a, b));
}
__device__ __forceinline__ float2 unpack_h2(unsigned u) {
    return __half22float2(__builtin_bit_cast(__half2, u));
}

__global__ __launch_bounds__(256) void pack_atoms_kernel(
    const float* __restrict__ q,
    const float* __restrict__ dip,
    const float* __restrict__ quad,
    f32x4* __restrict__ table,        // [N,2] 16B words
    int N)
{
    int i = blockIdx.x * blockDim.x + threadIdx.x;
    if (i >= N) return;
    const float* dp = dip + 3 * (size_t)i;
    const float* qp = quad + 9 * (size_t)i;

    f32x4 w0 = {q[i], dp[0], dp[1], dp[2]};

    float q00 = qp[0], q01 = qp[1], q02 = qp[2];
    float q10 = qp[3], q11 = qp[4], q12 = qp[5];
    float q20 = qp[6], q21 = qp[7], q22 = qp[8];
    float trQ3 = (q00 + q11 + q22) * (1.0f / 3.0f);

    u32x4 w1 = {pack_h2(q00 - trQ3, q11 - trQ3),
                pack_h2(q22 - trQ3, q01 + q10),
                pack_h2(q02 + q20, q12 + q21),
                0u};

    table[2 * (size_t)i + 0] = w0;
    table[2 * (size_t)i + 1] = __builtin_bit_cast(f32x4, w1);
}

__device__ __forceinline__ float edge_energy(
    float vx, float vy, float vz,
    f32x4 au, f32x4 av, u32x4 bv)
{
    float d2 = vx * vx + vy * vy + vz * vz;
    float d = sqrtf(d2);
    float inv_d = 1.0f / d;
    float inv_d2 = inv_d * inv_d;

    // poly5 switch, cutoff_sr = 4
    float x = d * 0.25f;
    float x2 = x * x;
    float x3 = x2 * x;
    float sw = 1.0f - x3 * (10.0f - 15.0f * x + 6.0f * x2);
    sw = (x < 1.0f) ? sw : 0.0f;
    float chi = sw * rsqrtf(d2 + 1.0f) + (1.0f - sw) * inv_d;

    // shifted-force corrections (cutoff = 10)
    float c1 = chi - (0.2f   - 0.01f   * d);
    float chi2 = chi * chi;
    float chi3 = chi2 * chi;
    float c2 = chi2 - (0.03f  - 0.002f  * d);
    float c3 = chi3 - (0.004f - 0.0003f * d);

    float qu = au.x, qv = av.x;
    float Ee = qu * qv * c1;

    float dot_uv = (vx * av.y + vy * av.z + vz * av.w) * inv_d;
    float dot_vu = (vx * au.y + vy * au.z + vz * au.w) * inv_d;
    float dd     = au.y * av.y + au.z * av.z + au.w * av.w;

    Ee += 2.0f * qu * dot_uv * c2;
    Ee += (dd - 3.0f * dot_uv * dot_vu) * c3;

    // traceless quadrupole contraction (uses sum(v_i^2) == d^2)
    float2 h0 = unpack_h2(bv.x);   // t00, t11
    float2 h1 = unpack_h2(bv.y);   // t22, s01
    float2 h2 = unpack_h2(bv.z);   // s02, s12
    float num = h0.x * vx * vx + h0.y * vy * vy + h1.x * vz * vz
              + h1.y * vx * vy + h2.x * vx * vz + h2.y * vy * vz;
    Ee += qu * (num * inv_d2) * c3;

    Ee *= KEHALF;
    return (d <= CUTOFF) ? Ee : 0.0f;
}

__global__ __launch_bounds__(256) void damped_elec_pipe(
    const f32x4* __restrict__ table,  // [N,2]
    const float* __restrict__ vec,    // [E,3]
    const int*   __restrict__ idx_u,  // [E]
    const int*   __restrict__ idx_v,  // [E]
    float*       __restrict__ out,    // [E]
    int E)
{
    int tid = blockIdx.x * blockDim.x + threadIdx.x;
    int stride = gridDim.x * blockDim.x;

    size_t i = tid;
    if (i >= (size_t)E) return;

    // ---- prologue: streams for the first edge ----
    int u = __builtin_nontemporal_load(idx_u + i);
    int v = __builtin_nontemporal_load(idx_v + i);
    float vx = __builtin_nontemporal_load(vec + 3 * i + 0);
    float vy = __builtin_nontemporal_load(vec + 3 * i + 1);
    float vz = __builtin_nontemporal_load(vec + 3 * i + 2);

    for (;;) {
        size_t inext = i + (size_t)stride;
        bool more = inext < (size_t)E;

        // 1) issue gathers for the CURRENT edge (idx already resident)
        f32x4 au = table[2 * (size_t)u];
        f32x4 av = table[2 * (size_t)v + 0];
        f32x4 bq = table[2 * (size_t)v + 1];

        // 2) issue NEXT edge's streams — independent, stay in flight
        //    through the compute below (vmcnt never drains to 0)
        int un = 0, vn = 0;
        float nx = 0.f, ny = 0.f, nz = 0.f;
        if (more) {
            un = __builtin_nontemporal_load(idx_u + inext);
            vn = __builtin_nontemporal_load(idx_v + inext);
            nx = __builtin_nontemporal_load(vec + 3 * inext + 0);
            ny = __builtin_nontemporal_load(vec + 3 * inext + 1);
            nz = __builtin_nontemporal_load(vec + 3 * inext + 2);
        }

        // 3) compute current edge (waits only on the gathers)
        float r = edge_energy(vx, vy, vz, au, av, __builtin_bit_cast(u32x4, bq));
        __builtin_nontemporal_store(r, out + i);

        if (!more) break;
        i = inext;
        u = un; v = vn; vx = nx; vy = ny; vz = nz;
    }
}

// Fallback if ws_size is too small for the packed table.
__global__ __launch_bounds__(256) void damped_elec_unpacked(
    const float* __restrict__ q,
    const float* __restrict__ dip,
    const float* __restrict__ quad,
    const float* __restrict__ vec,
    const int*   __restrict__ idx_u,
    const int*   __restrict__ idx_v,
    float*       __restrict__ out,
    int E)
{
    int i = blockIdx.x * blockDim.x + threadIdx.x;
    if (i >= E) return;
    float vx = vec[3 * (size_t)i + 0];
    float vy = vec[3 * (size_t)i + 1];
    float vz = vec[3 * (size_t)i + 2];
    int u = idx_u[i];
    int v = idx_v[i];
    const float* pu = dip + 3 * (size_t)u;
    const float* pv = dip + 3 * (size_t)v;
    const float* pq = quad + 9 * (size_t)v;

    f32x4 au = {q[u], pu[0], pu[1], pu[2]};
    f32x4 av = {q[v], pv[0], pv[1], pv[2]};
    float trQ3 = (pq[0] + pq[4] + pq[8]) * (1.0f / 3.0f);
    u32x4 bv = {pack_h2(pq[0] - trQ3, pq[4] - trQ3),
                pack_h2(pq[8] - trQ3, pq[1] + pq[3]),
                pack_h2(pq[2] + pq[6], pq[5] + pq[7]),
                0u};
    out[i] = edge_energy(vx, vy, vz, au, av, bv);
}

extern "C" void kernel_launch(void* const* d_in, const int* in_sizes, int n_in,
                              void* d_out, int out_size, void* d_ws, size_t ws_size,
                              hipStream_t stream) {
    const float* q    = (const float*)d_in[0];  // atomic_charges      [N]
    const float* dip  = (const float*)d_in[1];  // atomic_dipoles      [N,3]
    const float* quad = (const float*)d_in[2];  // atomic_quadrupoles  [N,3,3]
    const float* vec  = (const float*)d_in[3];  // vectors_uv          [E,3]
    const int*   iu   = (const int*)d_in[5];    // idx_u               [E]
    const int*   iv   = (const int*)d_in[6];    // idx_v               [E]
    float* out = (float*)d_out;

    int N = in_sizes[0];
    int E = in_sizes[4];
    int block = 256;

    size_t need = (size_t)N * 32;
    if (ws_size >= need) {
        f32x4* table = (f32x4*)d_ws;
        int pgrid = (N + block - 1) / block;
        pack_atoms_kernel<<<pgrid, block, 0, stream>>>(q, dip, quad, table, N);
        // 2048 blocks x 256 = full residency (32 waves/CU at low VGPR);
        // each thread pipelines ~E/524288 ~ 6 edges.
        int egrid = 2048;
        damped_elec_pipe<<<egrid, block, 0, stream>>>(table, vec, iu, iv, out, E);
    } else {
        int egrid = (E + block - 1) / block;
        damped_elec_unpacked<<<egrid, block, 0, stream>>>(q, dip, quad, vec, iu, iv, out, E);
    }
}